// Round 1
// baseline (134.651 us; speedup 1.0000x reference)
//
#include <hip/hip_runtime.h>
#include <cstddef>

// ---------------------------------------------------------------------------
// Transpose one level: (B, C=256, P) -> (B, P, C=256). P = H*W, multiple of 32.
// ---------------------------------------------------------------------------
__global__ __launch_bounds__(256) void tr_kernel(const float* __restrict__ in,
                                                 float* __restrict__ out, int P) {
  __shared__ float tile[32][33];
  int b  = blockIdx.z;
  int p0 = blockIdx.x << 5;
  int c0 = blockIdx.y << 5;
  int tx = threadIdx.x & 31;
  int ty = threadIdx.x >> 5;  // 0..7
  const float* inb  = in  + (size_t)b * 256 * P;
  float*       outb = out + (size_t)b * 256 * P;
#pragma unroll
  for (int i = 0; i < 4; ++i)
    tile[ty + i * 8][tx] = inb[(size_t)(c0 + ty + i * 8) * P + (p0 + tx)];
  __syncthreads();
#pragma unroll
  for (int i = 0; i < 4; ++i)
    outb[(size_t)(p0 + ty + i * 8) * 256 + (c0 + tx)] = tile[tx][ty + i * 8];
}

// ---------------------------------------------------------------------------
// RoI align
// ---------------------------------------------------------------------------
__device__ inline void interp1d(float c, int size, int& lo, int& hi,
                                float& fr, float& va) {
  va = (c >= -1.0f && c <= (float)size) ? 1.0f : 0.0f;
  float cc  = fmaxf(c, 0.0f);
  float lof = floorf(cc);
  if (lof >= (float)(size - 1)) {
    lo = size - 1; hi = size - 1; fr = 0.0f;
  } else {
    lo = (int)lof; hi = lo + 1; fr = cc - lof;
  }
}

template <bool NHWC>
__global__ __launch_bounds__(256) void roi_kernel(
    const float* __restrict__ f0, const float* __restrict__ f1,
    const float* __restrict__ f2, const float* __restrict__ f3,
    const float* __restrict__ bboxes, float* __restrict__ out, int R) {
  __shared__ float s_out[256 * 49];              // [c][bin]
  __shared__ int   s_lo[2][14], s_hi[2][14];     // [axis: 0=y 1=x][g]
  __shared__ float s_fr[2][14], s_va[2][14];

  int roi = blockIdx.x;
  int b   = roi / R;
  const float* bb = bboxes + (size_t)roi * 4;
  float x1 = bb[0], y1 = bb[1], x2 = bb[2], y2 = bb[3];

  float area  = (y2 - y1) * (x2 - x1);
  int   level = (area < 147456.0f) + (area < 36864.0f) + (area < 9216.0f);
  int   H     = 32 << level;                     // feature is H x H
  float scale = 1.0f / (float)(32 >> level);
  const float* fp = (level == 0) ? f0 : (level == 1) ? f1
                  : (level == 2) ? f2 : f3;
  fp += (size_t)b * 256 * H * H;                 // batch base, same both layouts

  float sx1 = x1 * scale, sy1 = y1 * scale;
  float sx2 = x2 * scale, sy2 = y2 * scale;
  float roi_w = fmaxf(sx2 - sx1, 1.0f);
  float roi_h = fmaxf(sy2 - sy1, 1.0f);
  float bin_w = roi_w / 7.0f;
  float bin_h = roi_h / 7.0f;

  int t = threadIdx.x;
  if (t < 28) {
    int   axis  = (t >= 14) ? 1 : 0;             // 0 = y, 1 = x
    int   g     = t - axis * 14;
    float start = axis ? sx1 : sy1;
    float binsz = axis ? bin_w : bin_h;
    float grid  = (float)(g >> 1) + 0.25f + 0.5f * (float)(g & 1);
    float c     = start + grid * binsz;
    int lo, hi; float fr, va;
    interp1d(c, H, lo, hi, fr, va);
    s_lo[axis][g] = lo; s_hi[axis][g] = hi;
    s_fr[axis][g] = fr; s_va[axis][g] = va;
  }
  __syncthreads();

  int wv = t >> 6, ln = t & 63;
  int c4 = ln * 4;                               // 4 channels per lane
  size_t chs = (size_t)H * H;

  for (int bin = wv; bin < 49; bin += 4) {
    int oy = bin / 7, ox = bin - oy * 7;
    float ax = 0.f, ay = 0.f, az = 0.f, aw = 0.f;
#pragma unroll
    for (int sy = 0; sy < 2; ++sy) {
#pragma unroll
      for (int sx = 0; sx < 2; ++sx) {
        int gy = oy * 2 + sy, gx = ox * 2 + sx;
        int   yl = s_lo[0][gy], yh = s_hi[0][gy];
        int   xl = s_lo[1][gx], xh = s_hi[1][gx];
        float fy = s_fr[0][gy], fx = s_fr[1][gx];
        float vv = s_va[0][gy] * s_va[1][gx];
        float w00 = (1.f - fy) * (1.f - fx) * vv;
        float w01 = (1.f - fy) * fx * vv;
        float w10 = fy * (1.f - fx) * vv;
        float w11 = fy * fx * vv;
        float4 p00, p01, p10, p11;
        if (NHWC) {
          p00 = *(const float4*)(fp + ((size_t)(yl * H + xl) * 256 + c4));
          p01 = *(const float4*)(fp + ((size_t)(yl * H + xh) * 256 + c4));
          p10 = *(const float4*)(fp + ((size_t)(yh * H + xl) * 256 + c4));
          p11 = *(const float4*)(fp + ((size_t)(yh * H + xh) * 256 + c4));
        } else {
          const float* base = fp + (size_t)c4 * chs;
          size_t i00 = (size_t)yl * H + xl, i01 = (size_t)yl * H + xh;
          size_t i10 = (size_t)yh * H + xl, i11 = (size_t)yh * H + xh;
          p00 = make_float4(base[i00], base[i00 + chs], base[i00 + 2 * chs], base[i00 + 3 * chs]);
          p01 = make_float4(base[i01], base[i01 + chs], base[i01 + 2 * chs], base[i01 + 3 * chs]);
          p10 = make_float4(base[i10], base[i10 + chs], base[i10 + 2 * chs], base[i10 + 3 * chs]);
          p11 = make_float4(base[i11], base[i11 + chs], base[i11 + 2 * chs], base[i11 + 3 * chs]);
        }
        ax += w00 * p00.x + w01 * p01.x + w10 * p10.x + w11 * p11.x;
        ay += w00 * p00.y + w01 * p01.y + w10 * p10.y + w11 * p11.y;
        az += w00 * p00.z + w01 * p01.z + w10 * p10.z + w11 * p11.z;
        aw += w00 * p00.w + w01 * p01.w + w10 * p10.w + w11 * p11.w;
      }
    }
    // stage as [c][bin] so the global write below is linear
    s_out[(c4 + 0) * 49 + bin] = ax * 0.25f;
    s_out[(c4 + 1) * 49 + bin] = ay * 0.25f;
    s_out[(c4 + 2) * 49 + bin] = az * 0.25f;
    s_out[(c4 + 3) * 49 + bin] = aw * 0.25f;
  }
  __syncthreads();

  float4*       o4 = (float4*)(out + (size_t)roi * (256 * 49));
  const float4* s4 = (const float4*)s_out;
  for (int i = t; i < 256 * 49 / 4; i += 256) o4[i] = s4[i];
}

// ---------------------------------------------------------------------------
extern "C" void kernel_launch(void* const* d_in, const int* in_sizes, int n_in,
                              void* d_out, int out_size, void* d_ws, size_t ws_size,
                              hipStream_t stream) {
  const float* f[4];
  for (int i = 0; i < 4; ++i) f[i] = (const float*)d_in[i];
  const float* bb  = (const float*)d_in[4];
  float*       out = (float*)d_out;

  int B = in_sizes[0] / (256 * 32 * 32);   // feat0 is (B,256,32,32)
  int N = in_sizes[4] / 4;                 // total rois
  int R = N / B;

  size_t off[4], tot = 0;
  for (int i = 0; i < 4; ++i) {
    int H = 32 << i;
    off[i] = tot;
    tot += (size_t)B * 256 * H * H;
  }

  if (ws_size >= tot * sizeof(float)) {
    float* ws = (float*)d_ws;
    for (int i = 0; i < 4; ++i) {
      int H = 32 << i;
      int P = H * H;
      dim3 grd(P / 32, 8, B);
      tr_kernel<<<grd, 256, 0, stream>>>(f[i], ws + off[i], P);
    }
    roi_kernel<true><<<N, 256, 0, stream>>>(ws + off[0], ws + off[1],
                                            ws + off[2], ws + off[3],
                                            bb, out, R);
  } else {
    roi_kernel<false><<<N, 256, 0, stream>>>(f[0], f[1], f[2], f[3],
                                             bb, out, R);
  }
}

// Round 3
// 83.919 us; speedup vs baseline: 1.6045x; 1.6045x over previous
//
#include <hip/hip_runtime.h>
#include <hip/hip_bf16.h>
#include <cstddef>

// ---------------------------------------------------------------------------
// bf16 helpers: bf16 pair packed in a uint (little-endian: low ushort = even ch)
// ---------------------------------------------------------------------------
__device__ __forceinline__ float bflo(unsigned u) { return __uint_as_float(u << 16); }
__device__ __forceinline__ float bfhi(unsigned u) { return __uint_as_float(u & 0xffff0000u); }

__device__ __forceinline__ void acc8(const uint4& q, float w, float* acc) {
  acc[0] = fmaf(w, bflo(q.x), acc[0]);
  acc[1] = fmaf(w, bfhi(q.x), acc[1]);
  acc[2] = fmaf(w, bflo(q.y), acc[2]);
  acc[3] = fmaf(w, bfhi(q.y), acc[3]);
  acc[4] = fmaf(w, bflo(q.z), acc[4]);
  acc[5] = fmaf(w, bfhi(q.z), acc[5]);
  acc[6] = fmaf(w, bflo(q.w), acc[6]);
  acc[7] = fmaf(w, bfhi(q.w), acc[7]);
}

// ---------------------------------------------------------------------------
// Merged transpose, all 4 levels: (B, 256, P) fp32 -> (B, P, 256) bf16 in ws.
// Tile: 32 pixels x 64 channels. Stores are 128 B contiguous per wave.
// ---------------------------------------------------------------------------
__global__ __launch_bounds__(256) void tr_all_kernel(
    const float* __restrict__ f0, const float* __restrict__ f1,
    const float* __restrict__ f2, const float* __restrict__ f3,
    ushort* __restrict__ ws,
    int c0_, int c1_, int c2_,          // cumulative block counts after lvl 0,1,2
    size_t o1, size_t o2, size_t o3) {  // ws element offsets of lvl 1,2,3
  __shared__ float tile[32][65];
  int bid = blockIdx.x;
  int lvl, lidx; const float* src; size_t off;
  if (bid < c0_)      { lvl = 0; lidx = bid;       src = f0; off = 0; }
  else if (bid < c1_) { lvl = 1; lidx = bid - c0_; src = f1; off = o1; }
  else if (bid < c2_) { lvl = 2; lidx = bid - c1_; src = f2; off = o2; }
  else                { lvl = 3; lidx = bid - c2_; src = f3; off = o3; }
  int H = 32 << lvl;
  int P = H * H;
  int nbp   = P >> 5;        // 32-pixel blocks
  int per_b = nbp * 4;       // 4 channel-blocks of 64
  int b  = lidx / per_b;
  int r  = lidx - b * per_b;
  int cb = r / nbp;
  int pb = r - cb * nbp;

  const float* in = src + ((size_t)b * 256 + cb * 64) * P + (size_t)pb * 32;
  int t  = threadIdx.x;
  int tx = t & 31, ty = t >> 5;        // ty 0..7
#pragma unroll
  for (int i = 0; i < 8; ++i) {
    int ch = ty * 8 + i;
    tile[tx][ch] = in[(size_t)ch * P + tx];
  }
  __syncthreads();
  ushort* outb = ws + off + ((size_t)b * P + (size_t)pb * 32) * 256 + cb * 64;
  int ln = t & 63, wv = t >> 6;        // wv 0..3
#pragma unroll
  for (int i = 0; i < 8; ++i) {
    int px = wv * 8 + i;
    __hip_bfloat16 v = __float2bfloat16(tile[px][ln]);   // RNE
    outb[(size_t)px * 256 + ln] = *reinterpret_cast<ushort*>(&v);
  }
}

// ---------------------------------------------------------------------------
__device__ __forceinline__ void interp1d(float c, int size, int& lo, int& hi,
                                         float& fr, float& va) {
  va = (c >= -1.0f && c <= (float)size) ? 1.0f : 0.0f;
  float cc  = fmaxf(c, 0.0f);
  float lof = floorf(cc);
  if (lof >= (float)(size - 1)) {
    lo = size - 1; hi = size - 1; fr = 0.0f;
  } else {
    lo = (int)lof; hi = lo + 1; fr = cc - lof;
  }
}

// ---------------------------------------------------------------------------
// RoI align from bf16 NHWC ws. Half-wave (32 lanes) per bin; lane = 8 channels
// via one 16 B load. 256 threads = 8 bins in flight.
// ---------------------------------------------------------------------------
__global__ __launch_bounds__(256) void roi_nhwc_kernel(
    const ushort* __restrict__ ws, const float* __restrict__ bboxes,
    float* __restrict__ out, int R, size_t o1, size_t o2, size_t o3) {
  __shared__ float s_out[256 * 49];              // [c][bin]
  __shared__ int   s_il[2][14], s_ih[2][14];     // [axis 0=y 1=x][g]
  __shared__ float s_fr[2][14], s_va[2][14];

  int roi = blockIdx.x;
  int b   = roi / R;
  const float* bb = bboxes + (size_t)roi * 4;
  float x1 = bb[0], y1 = bb[1], x2 = bb[2], y2 = bb[3];

  float area  = (y2 - y1) * (x2 - x1);
  int   level = (area < 147456.0f) + (area < 36864.0f) + (area < 9216.0f);
  int   H     = 32 << level;
  float scale = 1.0f / (float)(32 >> level);
  size_t off  = (level == 0) ? 0 : (level == 1) ? o1 : (level == 2) ? o2 : o3;
  const ushort* fp = ws + off + (size_t)b * H * H * 256;

  float sx1 = x1 * scale, sy1 = y1 * scale;
  float sx2 = x2 * scale, sy2 = y2 * scale;
  float bin_w = fmaxf(sx2 - sx1, 1.0f) / 7.0f;
  float bin_h = fmaxf(sy2 - sy1, 1.0f) / 7.0f;

  int t = threadIdx.x;
  if (t < 28) {
    int   axis  = (t >= 14) ? 1 : 0;
    int   g     = t - axis * 14;
    float start = axis ? sx1 : sy1;
    float binsz = axis ? bin_w : bin_h;
    float grid  = (float)(g >> 1) + 0.25f + 0.5f * (float)(g & 1);
    int lo, hi; float fr, va;
    interp1d(start + grid * binsz, H, lo, hi, fr, va);
    s_il[axis][g] = lo; s_ih[axis][g] = hi;
    s_fr[axis][g] = fr; s_va[axis][g] = va;
  }
  __syncthreads();

  int hw = t >> 5;          // half-wave 0..7
  int ln = t & 31;
  int c8 = ln * 8;

  for (int bin = hw; bin < 49; bin += 8) {
    int oy = bin / 7, ox = bin - oy * 7;
    float acc[8] = {0.f, 0.f, 0.f, 0.f, 0.f, 0.f, 0.f, 0.f};
#pragma unroll
    for (int sy = 0; sy < 2; ++sy) {
#pragma unroll
      for (int sx = 0; sx < 2; ++sx) {
        int gy = oy * 2 + sy, gx = ox * 2 + sx;
        int   yl = s_il[0][gy], yh = s_ih[0][gy];
        int   xl = s_il[1][gx], xh = s_ih[1][gx];
        float fy = s_fr[0][gy], fx = s_fr[1][gx];
        float vv = s_va[0][gy] * s_va[1][gx];
        float w00 = (1.f - fy) * (1.f - fx) * vv;
        float w01 = (1.f - fy) * fx * vv;
        float w10 = fy * (1.f - fx) * vv;
        float w11 = fy * fx * vv;
        uint4 q00 = *(const uint4*)(fp + ((size_t)(yl * H + xl) * 256 + c8));
        uint4 q01 = *(const uint4*)(fp + ((size_t)(yl * H + xh) * 256 + c8));
        uint4 q10 = *(const uint4*)(fp + ((size_t)(yh * H + xl) * 256 + c8));
        uint4 q11 = *(const uint4*)(fp + ((size_t)(yh * H + xh) * 256 + c8));
        acc8(q00, w00, acc);
        acc8(q01, w01, acc);
        acc8(q10, w10, acc);
        acc8(q11, w11, acc);
      }
    }
#pragma unroll
    for (int k = 0; k < 8; ++k) s_out[(c8 + k) * 49 + bin] = acc[k] * 0.25f;
  }
  __syncthreads();

  float4*       o4 = (float4*)(out + (size_t)roi * (256 * 49));
  const float4* s4 = (const float4*)s_out;
  for (int i = t; i < 256 * 49 / 4; i += 256) o4[i] = s4[i];
}

// ---------------------------------------------------------------------------
// Fallback: direct NCHW fp32 (used only if ws too small)
// ---------------------------------------------------------------------------
__global__ __launch_bounds__(256) void roi_nchw_kernel(
    const float* __restrict__ f0, const float* __restrict__ f1,
    const float* __restrict__ f2, const float* __restrict__ f3,
    const float* __restrict__ bboxes, float* __restrict__ out, int R) {
  __shared__ float s_out[256 * 49];
  __shared__ int   s_il[2][14], s_ih[2][14];
  __shared__ float s_fr[2][14], s_va[2][14];

  int roi = blockIdx.x;
  int b   = roi / R;
  const float* bb = bboxes + (size_t)roi * 4;
  float x1 = bb[0], y1 = bb[1], x2 = bb[2], y2 = bb[3];
  float area  = (y2 - y1) * (x2 - x1);
  int   level = (area < 147456.0f) + (area < 36864.0f) + (area < 9216.0f);
  int   H     = 32 << level;
  float scale = 1.0f / (float)(32 >> level);
  const float* fp = (level == 0) ? f0 : (level == 1) ? f1
                  : (level == 2) ? f2 : f3;
  fp += (size_t)b * 256 * H * H;

  float sx1 = x1 * scale, sy1 = y1 * scale;
  float sx2 = x2 * scale, sy2 = y2 * scale;
  float bin_w = fmaxf(sx2 - sx1, 1.0f) / 7.0f;
  float bin_h = fmaxf(sy2 - sy1, 1.0f) / 7.0f;

  int t = threadIdx.x;
  if (t < 28) {
    int   axis  = (t >= 14) ? 1 : 0;
    int   g     = t - axis * 14;
    float start = axis ? sx1 : sy1;
    float binsz = axis ? bin_w : bin_h;
    float grid  = (float)(g >> 1) + 0.25f + 0.5f * (float)(g & 1);
    int lo, hi; float fr, va;
    interp1d(start + grid * binsz, H, lo, hi, fr, va);
    s_il[axis][g] = lo; s_ih[axis][g] = hi;
    s_fr[axis][g] = fr; s_va[axis][g] = va;
  }
  __syncthreads();

  int wv = t >> 6, ln = t & 63;
  int c4 = ln * 4;
  size_t chs = (size_t)H * H;

  for (int bin = wv; bin < 49; bin += 4) {
    int oy = bin / 7, ox = bin - oy * 7;
    float a0 = 0.f, a1 = 0.f, a2 = 0.f, a3 = 0.f;
#pragma unroll
    for (int sy = 0; sy < 2; ++sy) {
#pragma unroll
      for (int sx = 0; sx < 2; ++sx) {
        int gy = oy * 2 + sy, gx = ox * 2 + sx;
        int   yl = s_il[0][gy], yh = s_ih[0][gy];
        int   xl = s_il[1][gx], xh = s_ih[1][gx];
        float fy = s_fr[0][gy], fx = s_fr[1][gx];
        float vv = s_va[0][gy] * s_va[1][gx];
        float w00 = (1.f - fy) * (1.f - fx) * vv;
        float w01 = (1.f - fy) * fx * vv;
        float w10 = fy * (1.f - fx) * vv;
        float w11 = fy * fx * vv;
        const float* base = fp + (size_t)c4 * chs;
        size_t i00 = (size_t)yl * H + xl, i01 = (size_t)yl * H + xh;
        size_t i10 = (size_t)yh * H + xl, i11 = (size_t)yh * H + xh;
#pragma unroll
        for (int k = 0; k < 4; ++k) {
          float v = w00 * base[i00 + k * chs] + w01 * base[i01 + k * chs] +
                    w10 * base[i10 + k * chs] + w11 * base[i11 + k * chs];
          if (k == 0) a0 += v; else if (k == 1) a1 += v;
          else if (k == 2) a2 += v; else a3 += v;
        }
      }
    }
    s_out[(c4 + 0) * 49 + bin] = a0 * 0.25f;
    s_out[(c4 + 1) * 49 + bin] = a1 * 0.25f;
    s_out[(c4 + 2) * 49 + bin] = a2 * 0.25f;
    s_out[(c4 + 3) * 49 + bin] = a3 * 0.25f;
  }
  __syncthreads();

  float4*       o4 = (float4*)(out + (size_t)roi * (256 * 49));
  const float4* s4 = (const float4*)s_out;
  for (int i = t; i < 256 * 49 / 4; i += 256) o4[i] = s4[i];
}

// ---------------------------------------------------------------------------
extern "C" void kernel_launch(void* const* d_in, const int* in_sizes, int n_in,
                              void* d_out, int out_size, void* d_ws, size_t ws_size,
                              hipStream_t stream) {
  const float* f[4];
  for (int i = 0; i < 4; ++i) f[i] = (const float*)d_in[i];
  const float* bb  = (const float*)d_in[4];
  float*       out = (float*)d_out;

  int B = in_sizes[0] / (256 * 32 * 32);
  int N = in_sizes[4] / 4;
  int R = N / B;

  size_t P[4] = {1024, 4096, 16384, 65536};
  size_t o1 = (size_t)B * 256 * P[0];
  size_t o2 = o1 + (size_t)B * 256 * P[1];
  size_t o3 = o2 + (size_t)B * 256 * P[2];
  size_t tot = o3 + (size_t)B * 256 * P[3];

  if (ws_size >= tot * sizeof(ushort)) {
    ushort* ws = (ushort*)d_ws;
    int n0 = B * 4 * (int)(P[0] >> 5);
    int n1 = B * 4 * (int)(P[1] >> 5);
    int n2 = B * 4 * (int)(P[2] >> 5);
    int n3 = B * 4 * (int)(P[3] >> 5);
    int c0 = n0, c1 = c0 + n1, c2 = c1 + n2, ctot = c2 + n3;
    tr_all_kernel<<<ctot, 256, 0, stream>>>(f[0], f[1], f[2], f[3], ws,
                                            c0, c1, c2, o1, o2, o3);
    roi_nhwc_kernel<<<N, 256, 0, stream>>>(ws, bb, out, R, o1, o2, o3);
  } else {
    roi_nchw_kernel<<<N, 256, 0, stream>>>(f[0], f[1], f[2], f[3], bb, out, R);
  }
}

// Round 4
// 81.564 us; speedup vs baseline: 1.6509x; 1.0289x over previous
//
#include <hip/hip_runtime.h>
#include <hip/hip_bf16.h>
#include <cstddef>

// ---------------------------------------------------------------------------
// bf16 helpers: bf16 pair packed in a uint (low ushort = even channel)
// ---------------------------------------------------------------------------
__device__ __forceinline__ float bflo(unsigned u) { return __uint_as_float(u << 16); }
__device__ __forceinline__ float bfhi(unsigned u) { return __uint_as_float(u & 0xffff0000u); }

__device__ __forceinline__ unsigned pk(float lo, float hi) {
  __hip_bfloat162 h = __float22bfloat162_rn(float2{lo, hi});
  return *reinterpret_cast<unsigned*>(&h);
}

__device__ __forceinline__ void acc8(const uint4& q, float w, float* acc) {
  acc[0] = fmaf(w, bflo(q.x), acc[0]);
  acc[1] = fmaf(w, bfhi(q.x), acc[1]);
  acc[2] = fmaf(w, bflo(q.y), acc[2]);
  acc[3] = fmaf(w, bfhi(q.y), acc[3]);
  acc[4] = fmaf(w, bflo(q.z), acc[4]);
  acc[5] = fmaf(w, bfhi(q.z), acc[5]);
  acc[6] = fmaf(w, bflo(q.w), acc[6]);
  acc[7] = fmaf(w, bfhi(q.w), acc[7]);
}

// ---------------------------------------------------------------------------
// Merged transpose, all 4 levels: (B, 256, P) fp32 -> (B, P, 256) bf16 in ws.
// Block tile: 64 pixels x 256 channels.
//   loads : float4 (4 px) per instr, 256 B contiguous per 16 lanes
//   stores: uint4 (8 ch) per instr, 1 KB contiguous per wave
// LDS: uint tile[64][132]  (row stride 132 -> uint4 rows stay 16 B aligned)
// ---------------------------------------------------------------------------
__global__ __launch_bounds__(256) void tr_all_kernel(
    const float* __restrict__ f0, const float* __restrict__ f1,
    const float* __restrict__ f2, const float* __restrict__ f3,
    ushort* __restrict__ ws,
    int c0_, int c1_, int c2_,          // cumulative tile counts after lvl 0,1,2
    size_t o1, size_t o2, size_t o3) {  // ws element offsets of lvl 1,2,3
  __shared__ unsigned tile[64 * 132];
  int bid = blockIdx.x;
  int lvl, lidx; const float* src; size_t off;
  if (bid < c0_)      { lvl = 0; lidx = bid;       src = f0; off = 0; }
  else if (bid < c1_) { lvl = 1; lidx = bid - c0_; src = f1; off = o1; }
  else if (bid < c2_) { lvl = 2; lidx = bid - c1_; src = f2; off = o2; }
  else                { lvl = 3; lidx = bid - c2_; src = f3; off = o3; }
  int H = 32 << lvl;
  int P = H * H;
  int tpb = P >> 6;                 // 64-px tiles per image
  int b  = lidx / tpb;
  int tp = lidx - b * tpb;

  const float* in = src + (size_t)b * 256 * P + (size_t)tp * 64;
  int t  = threadIdx.x;
  int pg = t & 15;                  // pixel group (4 px each)
  int cp = t >> 4;                  // channel-pair group 0..15
#pragma unroll
  for (int i = 0; i < 8; ++i) {
    int col = cp + 16 * i;          // uint column = channel pair index
    int ch  = col * 2;
    float4 a = *(const float4*)(in + (size_t)ch * P + pg * 4);
    float4 c = *(const float4*)(in + (size_t)(ch + 1) * P + pg * 4);
    int row = pg * 4;
    tile[(row + 0) * 132 + col] = pk(a.x, c.x);
    tile[(row + 1) * 132 + col] = pk(a.y, c.y);
    tile[(row + 2) * 132 + col] = pk(a.z, c.z);
    tile[(row + 3) * 132 + col] = pk(a.w, c.w);
  }
  __syncthreads();

  ushort* outp = ws + off + ((size_t)b * P + (size_t)tp * 64) * 256;
  int cg  = t & 31;                 // uint4 group within pixel row (8 ch)
  int px8 = t >> 5;                 // 0..7
#pragma unroll
  for (int i = 0; i < 8; ++i) {
    int pxi = px8 + 8 * i;
    uint4 v = *(const uint4*)&tile[pxi * 132 + cg * 4];
    *(uint4*)(outp + (size_t)pxi * 256 + cg * 8) = v;
  }
}

// ---------------------------------------------------------------------------
__device__ __forceinline__ void interp1d(float c, int size, int& lo, int& hi,
                                         float& fr, float& va) {
  va = (c >= -1.0f && c <= (float)size) ? 1.0f : 0.0f;
  float cc  = fmaxf(c, 0.0f);
  float lof = floorf(cc);
  if (lof >= (float)(size - 1)) {
    lo = size - 1; hi = size - 1; fr = 0.0f;
  } else {
    lo = (int)lof; hi = lo + 1; fr = cc - lof;
  }
}

// ---------------------------------------------------------------------------
// RoI align from bf16 NHWC ws. Half-wave (32 lanes) per bin; lane = 8 channels
// via one 16 B load. 256 threads = 8 bins in flight.
// ---------------------------------------------------------------------------
__global__ __launch_bounds__(256) void roi_nhwc_kernel(
    const ushort* __restrict__ ws, const float* __restrict__ bboxes,
    float* __restrict__ out, int R, size_t o1, size_t o2, size_t o3) {
  __shared__ float s_out[256 * 49];              // [c][bin]
  __shared__ int   s_il[2][14], s_ih[2][14];     // [axis 0=y 1=x][g]
  __shared__ float s_fr[2][14], s_va[2][14];

  int roi = blockIdx.x;
  int b   = roi / R;
  const float* bb = bboxes + (size_t)roi * 4;
  float x1 = bb[0], y1 = bb[1], x2 = bb[2], y2 = bb[3];

  float area  = (y2 - y1) * (x2 - x1);
  int   level = (area < 147456.0f) + (area < 36864.0f) + (area < 9216.0f);
  int   H     = 32 << level;
  float scale = 1.0f / (float)(32 >> level);
  size_t off  = (level == 0) ? 0 : (level == 1) ? o1 : (level == 2) ? o2 : o3;
  const ushort* fp = ws + off + (size_t)b * H * H * 256;

  float sx1 = x1 * scale, sy1 = y1 * scale;
  float sx2 = x2 * scale, sy2 = y2 * scale;
  float bin_w = fmaxf(sx2 - sx1, 1.0f) / 7.0f;
  float bin_h = fmaxf(sy2 - sy1, 1.0f) / 7.0f;

  int t = threadIdx.x;
  if (t < 28) {
    int   axis  = (t >= 14) ? 1 : 0;
    int   g     = t - axis * 14;
    float start = axis ? sx1 : sy1;
    float binsz = axis ? bin_w : bin_h;
    float grid  = (float)(g >> 1) + 0.25f + 0.5f * (float)(g & 1);
    int lo, hi; float fr, va;
    interp1d(start + grid * binsz, H, lo, hi, fr, va);
    s_il[axis][g] = lo; s_ih[axis][g] = hi;
    s_fr[axis][g] = fr; s_va[axis][g] = va;
  }
  __syncthreads();

  int hw = t >> 5;          // half-wave 0..7
  int ln = t & 31;
  int c8 = ln * 8;

  for (int bin = hw; bin < 49; bin += 8) {
    int oy = bin / 7, ox = bin - oy * 7;
    float acc[8] = {0.f, 0.f, 0.f, 0.f, 0.f, 0.f, 0.f, 0.f};
#pragma unroll
    for (int sy = 0; sy < 2; ++sy) {
#pragma unroll
      for (int sx = 0; sx < 2; ++sx) {
        int gy = oy * 2 + sy, gx = ox * 2 + sx;
        int   yl = s_il[0][gy], yh = s_ih[0][gy];
        int   xl = s_il[1][gx], xh = s_ih[1][gx];
        float fy = s_fr[0][gy], fx = s_fr[1][gx];
        float vv = s_va[0][gy] * s_va[1][gx];
        float w00 = (1.f - fy) * (1.f - fx) * vv;
        float w01 = (1.f - fy) * fx * vv;
        float w10 = fy * (1.f - fx) * vv;
        float w11 = fy * fx * vv;
        uint4 q00 = *(const uint4*)(fp + ((size_t)(yl * H + xl) * 256 + c8));
        uint4 q01 = *(const uint4*)(fp + ((size_t)(yl * H + xh) * 256 + c8));
        uint4 q10 = *(const uint4*)(fp + ((size_t)(yh * H + xl) * 256 + c8));
        uint4 q11 = *(const uint4*)(fp + ((size_t)(yh * H + xh) * 256 + c8));
        acc8(q00, w00, acc);
        acc8(q01, w01, acc);
        acc8(q10, w10, acc);
        acc8(q11, w11, acc);
      }
    }
#pragma unroll
    for (int k = 0; k < 8; ++k) s_out[(c8 + k) * 49 + bin] = acc[k] * 0.25f;
  }
  __syncthreads();

  float4*       o4 = (float4*)(out + (size_t)roi * (256 * 49));
  const float4* s4 = (const float4*)s_out;
  for (int i = t; i < 256 * 49 / 4; i += 256) o4[i] = s4[i];
}

// ---------------------------------------------------------------------------
// Fallback: direct NCHW fp32 (used only if ws too small)
// ---------------------------------------------------------------------------
__global__ __launch_bounds__(256) void roi_nchw_kernel(
    const float* __restrict__ f0, const float* __restrict__ f1,
    const float* __restrict__ f2, const float* __restrict__ f3,
    const float* __restrict__ bboxes, float* __restrict__ out, int R) {
  __shared__ float s_out[256 * 49];
  __shared__ int   s_il[2][14], s_ih[2][14];
  __shared__ float s_fr[2][14], s_va[2][14];

  int roi = blockIdx.x;
  int b   = roi / R;
  const float* bb = bboxes + (size_t)roi * 4;
  float x1 = bb[0], y1 = bb[1], x2 = bb[2], y2 = bb[3];
  float area  = (y2 - y1) * (x2 - x1);
  int   level = (area < 147456.0f) + (area < 36864.0f) + (area < 9216.0f);
  int   H     = 32 << level;
  float scale = 1.0f / (float)(32 >> level);
  const float* fp = (level == 0) ? f0 : (level == 1) ? f1
                  : (level == 2) ? f2 : f3;
  fp += (size_t)b * 256 * H * H;

  float sx1 = x1 * scale, sy1 = y1 * scale;
  float sx2 = x2 * scale, sy2 = y2 * scale;
  float bin_w = fmaxf(sx2 - sx1, 1.0f) / 7.0f;
  float bin_h = fmaxf(sy2 - sy1, 1.0f) / 7.0f;

  int t = threadIdx.x;
  if (t < 28) {
    int   axis  = (t >= 14) ? 1 : 0;
    int   g     = t - axis * 14;
    float start = axis ? sx1 : sy1;
    float binsz = axis ? bin_w : bin_h;
    float grid  = (float)(g >> 1) + 0.25f + 0.5f * (float)(g & 1);
    int lo, hi; float fr, va;
    interp1d(start + grid * binsz, H, lo, hi, fr, va);
    s_il[axis][g] = lo; s_ih[axis][g] = hi;
    s_fr[axis][g] = fr; s_va[axis][g] = va;
  }
  __syncthreads();

  int wv = t >> 6, ln = t & 63;
  int c4 = ln * 4;
  size_t chs = (size_t)H * H;

  for (int bin = wv; bin < 49; bin += 4) {
    int oy = bin / 7, ox = bin - oy * 7;
    float a0 = 0.f, a1 = 0.f, a2 = 0.f, a3 = 0.f;
#pragma unroll
    for (int sy = 0; sy < 2; ++sy) {
#pragma unroll
      for (int sx = 0; sx < 2; ++sx) {
        int gy = oy * 2 + sy, gx = ox * 2 + sx;
        int   yl = s_il[0][gy], yh = s_ih[0][gy];
        int   xl = s_il[1][gx], xh = s_ih[1][gx];
        float fy = s_fr[0][gy], fx = s_fr[1][gx];
        float vv = s_va[0][gy] * s_va[1][gx];
        float w00 = (1.f - fy) * (1.f - fx) * vv;
        float w01 = (1.f - fy) * fx * vv;
        float w10 = fy * (1.f - fx) * vv;
        float w11 = fy * fx * vv;
        const float* base = fp + (size_t)c4 * chs;
        size_t i00 = (size_t)yl * H + xl, i01 = (size_t)yl * H + xh;
        size_t i10 = (size_t)yh * H + xl, i11 = (size_t)yh * H + xh;
#pragma unroll
        for (int k = 0; k < 4; ++k) {
          float v = w00 * base[i00 + k * chs] + w01 * base[i01 + k * chs] +
                    w10 * base[i10 + k * chs] + w11 * base[i11 + k * chs];
          if (k == 0) a0 += v; else if (k == 1) a1 += v;
          else if (k == 2) a2 += v; else a3 += v;
        }
      }
    }
    s_out[(c4 + 0) * 49 + bin] = a0 * 0.25f;
    s_out[(c4 + 1) * 49 + bin] = a1 * 0.25f;
    s_out[(c4 + 2) * 49 + bin] = a2 * 0.25f;
    s_out[(c4 + 3) * 49 + bin] = a3 * 0.25f;
  }
  __syncthreads();

  float4*       o4 = (float4*)(out + (size_t)roi * (256 * 49));
  const float4* s4 = (const float4*)s_out;
  for (int i = t; i < 256 * 49 / 4; i += 256) o4[i] = s4[i];
}

// ---------------------------------------------------------------------------
extern "C" void kernel_launch(void* const* d_in, const int* in_sizes, int n_in,
                              void* d_out, int out_size, void* d_ws, size_t ws_size,
                              hipStream_t stream) {
  const float* f[4];
  for (int i = 0; i < 4; ++i) f[i] = (const float*)d_in[i];
  const float* bb  = (const float*)d_in[4];
  float*       out = (float*)d_out;

  int B = in_sizes[0] / (256 * 32 * 32);
  int N = in_sizes[4] / 4;
  int R = N / B;

  size_t P[4] = {1024, 4096, 16384, 65536};
  size_t o1 = (size_t)B * 256 * P[0];
  size_t o2 = o1 + (size_t)B * 256 * P[1];
  size_t o3 = o2 + (size_t)B * 256 * P[2];
  size_t tot = o3 + (size_t)B * 256 * P[3];

  if (ws_size >= tot * sizeof(ushort)) {
    ushort* ws = (ushort*)d_ws;
    int n0 = B * (int)(P[0] >> 6);
    int n1 = B * (int)(P[1] >> 6);
    int n2 = B * (int)(P[2] >> 6);
    int n3 = B * (int)(P[3] >> 6);
    int c0 = n0, c1 = c0 + n1, c2 = c1 + n2, ctot = c2 + n3;
    tr_all_kernel<<<ctot, 256, 0, stream>>>(f[0], f[1], f[2], f[3], ws,
                                            c0, c1, c2, o1, o2, o3);
    roi_nhwc_kernel<<<N, 256, 0, stream>>>(ws, bb, out, R, o1, o2, o3);
  } else {
    roi_nchw_kernel<<<N, 256, 0, stream>>>(f[0], f[1], f[2], f[3], bb, out, R);
  }
}

// Round 5
// 80.846 us; speedup vs baseline: 1.6655x; 1.0089x over previous
//
#include <hip/hip_runtime.h>
#include <hip/hip_bf16.h>
#include <cstddef>

// ---------------------------------------------------------------------------
// bf16 helpers: bf16 pair packed in a uint (low ushort = even channel)
// ---------------------------------------------------------------------------
__device__ __forceinline__ float bflo(unsigned u) { return __uint_as_float(u << 16); }
__device__ __forceinline__ float bfhi(unsigned u) { return __uint_as_float(u & 0xffff0000u); }

__device__ __forceinline__ unsigned pk(float lo, float hi) {
  __hip_bfloat162 h = __float22bfloat162_rn(float2{lo, hi});
  return *reinterpret_cast<unsigned*>(&h);
}

__device__ __forceinline__ void acc8(const uint4& q, float w, float* acc) {
  acc[0] = fmaf(w, bflo(q.x), acc[0]);
  acc[1] = fmaf(w, bfhi(q.x), acc[1]);
  acc[2] = fmaf(w, bflo(q.y), acc[2]);
  acc[3] = fmaf(w, bfhi(q.y), acc[3]);
  acc[4] = fmaf(w, bflo(q.z), acc[4]);
  acc[5] = fmaf(w, bfhi(q.z), acc[5]);
  acc[6] = fmaf(w, bflo(q.w), acc[6]);
  acc[7] = fmaf(w, bfhi(q.w), acc[7]);
}

// ---------------------------------------------------------------------------
// Merged transpose, all 4 levels: (B, 256, P) fp32 -> (B, P, 256) bf16 in ws.
// Block tile: 256 px x 64 ch. Each load instr = 1 KB contiguous within one
// channel; consecutive blocks sweep px linearly (long DRAM streams).
// LDS pair-major: uint tile[32][260]; writes are lane-contiguous b128
// (conflict-free), reads are b32 4-way (pad 260 = 4 mod 32).
// ---------------------------------------------------------------------------
__global__ __launch_bounds__(256) void tr_all_kernel(
    const float* __restrict__ f0, const float* __restrict__ f1,
    const float* __restrict__ f2, const float* __restrict__ f3,
    ushort* __restrict__ ws,
    int c0_, int c1_, int c2_, int B,   // cumulative block counts, batch size
    size_t o1, size_t o2, size_t o3) {  // ws element offsets of lvl 1,2,3
  __shared__ unsigned tile[32 * 260];
  int bid = blockIdx.x;
  int lvl, lidx; const float* src; size_t off;
  if (bid < c0_)      { lvl = 0; lidx = bid;       src = f0; off = 0; }
  else if (bid < c1_) { lvl = 1; lidx = bid - c0_; src = f1; off = o1; }
  else if (bid < c2_) { lvl = 2; lidx = bid - c1_; src = f2; off = o2; }
  else                { lvl = 3; lidx = bid - c2_; src = f3; off = o3; }
  int H   = 32 << lvl;
  int P   = H * H;
  int npx = P >> 8;                  // 256-px chunks per image
  int chg = lidx / (B * npx);        // channel group 0..3 (outermost)
  int rem = lidx - chg * (B * npx);
  int b   = rem / npx;
  int pxc = rem & (npx - 1);         // px chunk (innermost -> linear sweep)

  const float* in = src + ((size_t)b * 256 + chg * 64) * P + (size_t)pxc * 256;
  int t = threadIdx.x;
  int l = t & 63, wv = t >> 6;
#pragma unroll
  for (int j = 0; j < 8; ++j) {
    int ch = wv * 16 + 2 * j;
    float4 a = *(const float4*)(in + (size_t)ch * P + l * 4);
    float4 c = *(const float4*)(in + (size_t)(ch + 1) * P + l * 4);
    int pair = wv * 8 + j;           // 0..31
    uint4 v;
    v.x = pk(a.x, c.x); v.y = pk(a.y, c.y);
    v.z = pk(a.z, c.z); v.w = pk(a.w, c.w);
    *(uint4*)&tile[pair * 260 + l * 4] = v;
  }
  __syncthreads();

  ushort* outp = ws + off + ((size_t)b * P + (size_t)pxc * 256) * 256 + chg * 64;
  int cg = t & 7;                    // uint4 index within 64-ch segment
  int p0 = t >> 3;                   // 0..31
#pragma unroll
  for (int i = 0; i < 8; ++i) {
    int pxi = p0 + 32 * i;
    uint4 g;
    g.x = tile[(cg * 4 + 0) * 260 + pxi];
    g.y = tile[(cg * 4 + 1) * 260 + pxi];
    g.z = tile[(cg * 4 + 2) * 260 + pxi];
    g.w = tile[(cg * 4 + 3) * 260 + pxi];
    *(uint4*)(outp + (size_t)pxi * 256 + cg * 8) = g;
  }
}

// ---------------------------------------------------------------------------
__device__ __forceinline__ void interp1d(float c, int size, int& lo, int& hi,
                                         float& fr, float& va) {
  va = (c >= -1.0f && c <= (float)size) ? 1.0f : 0.0f;
  float cc  = fmaxf(c, 0.0f);
  float lof = floorf(cc);
  if (lof >= (float)(size - 1)) {
    lo = size - 1; hi = size - 1; fr = 0.0f;
  } else {
    lo = (int)lof; hi = lo + 1; fr = cc - lof;
  }
}

// ---------------------------------------------------------------------------
// RoI align from bf16 NHWC ws. Half-wave (32 lanes) per bin; lane = 8 channels
// via one 16 B load. 256 threads = 8 bins in flight.
// ---------------------------------------------------------------------------
__global__ __launch_bounds__(256) void roi_nhwc_kernel(
    const ushort* __restrict__ ws, const float* __restrict__ bboxes,
    float* __restrict__ out, int R, size_t o1, size_t o2, size_t o3) {
  __shared__ float s_out[256 * 49];              // [c][bin]
  __shared__ int   s_il[2][14], s_ih[2][14];     // [axis 0=y 1=x][g]
  __shared__ float s_fr[2][14], s_va[2][14];

  int roi = blockIdx.x;
  int b   = roi / R;
  const float* bb = bboxes + (size_t)roi * 4;
  float x1 = bb[0], y1 = bb[1], x2 = bb[2], y2 = bb[3];

  float area  = (y2 - y1) * (x2 - x1);
  int   level = (area < 147456.0f) + (area < 36864.0f) + (area < 9216.0f);
  int   H     = 32 << level;
  float scale = 1.0f / (float)(32 >> level);
  size_t off  = (level == 0) ? 0 : (level == 1) ? o1 : (level == 2) ? o2 : o3;
  const ushort* fp = ws + off + (size_t)b * H * H * 256;

  float sx1 = x1 * scale, sy1 = y1 * scale;
  float sx2 = x2 * scale, sy2 = y2 * scale;
  float bin_w = fmaxf(sx2 - sx1, 1.0f) / 7.0f;
  float bin_h = fmaxf(sy2 - sy1, 1.0f) / 7.0f;

  int t = threadIdx.x;
  if (t < 28) {
    int   axis  = (t >= 14) ? 1 : 0;
    int   g     = t - axis * 14;
    float start = axis ? sx1 : sy1;
    float binsz = axis ? bin_w : bin_h;
    float grid  = (float)(g >> 1) + 0.25f + 0.5f * (float)(g & 1);
    int lo, hi; float fr, va;
    interp1d(start + grid * binsz, H, lo, hi, fr, va);
    s_il[axis][g] = lo; s_ih[axis][g] = hi;
    s_fr[axis][g] = fr; s_va[axis][g] = va;
  }
  __syncthreads();

  int hw = t >> 5;          // half-wave 0..7
  int ln = t & 31;
  int c8 = ln * 8;

  for (int bin = hw; bin < 49; bin += 8) {
    int oy = bin / 7, ox = bin - oy * 7;
    float acc[8] = {0.f, 0.f, 0.f, 0.f, 0.f, 0.f, 0.f, 0.f};
#pragma unroll
    for (int sy = 0; sy < 2; ++sy) {
#pragma unroll
      for (int sx = 0; sx < 2; ++sx) {
        int gy = oy * 2 + sy, gx = ox * 2 + sx;
        int   yl = s_il[0][gy], yh = s_ih[0][gy];
        int   xl = s_il[1][gx], xh = s_ih[1][gx];
        float fy = s_fr[0][gy], fx = s_fr[1][gx];
        float vv = s_va[0][gy] * s_va[1][gx];
        float w00 = (1.f - fy) * (1.f - fx) * vv;
        float w01 = (1.f - fy) * fx * vv;
        float w10 = fy * (1.f - fx) * vv;
        float w11 = fy * fx * vv;
        uint4 q00 = *(const uint4*)(fp + ((size_t)(yl * H + xl) * 256 + c8));
        uint4 q01 = *(const uint4*)(fp + ((size_t)(yl * H + xh) * 256 + c8));
        uint4 q10 = *(const uint4*)(fp + ((size_t)(yh * H + xl) * 256 + c8));
        uint4 q11 = *(const uint4*)(fp + ((size_t)(yh * H + xh) * 256 + c8));
        acc8(q00, w00, acc);
        acc8(q01, w01, acc);
        acc8(q10, w10, acc);
        acc8(q11, w11, acc);
      }
    }
#pragma unroll
    for (int k = 0; k < 8; ++k) s_out[(c8 + k) * 49 + bin] = acc[k] * 0.25f;
  }
  __syncthreads();

  float4*       o4 = (float4*)(out + (size_t)roi * (256 * 49));
  const float4* s4 = (const float4*)s_out;
  for (int i = t; i < 256 * 49 / 4; i += 256) o4[i] = s4[i];
}

// ---------------------------------------------------------------------------
// Fallback: direct NCHW fp32 (used only if ws too small)
// ---------------------------------------------------------------------------
__global__ __launch_bounds__(256) void roi_nchw_kernel(
    const float* __restrict__ f0, const float* __restrict__ f1,
    const float* __restrict__ f2, const float* __restrict__ f3,
    const float* __restrict__ bboxes, float* __restrict__ out, int R) {
  __shared__ float s_out[256 * 49];
  __shared__ int   s_il[2][14], s_ih[2][14];
  __shared__ float s_fr[2][14], s_va[2][14];

  int roi = blockIdx.x;
  int b   = roi / R;
  const float* bb = bboxes + (size_t)roi * 4;
  float x1 = bb[0], y1 = bb[1], x2 = bb[2], y2 = bb[3];
  float area  = (y2 - y1) * (x2 - x1);
  int   level = (area < 147456.0f) + (area < 36864.0f) + (area < 9216.0f);
  int   H     = 32 << level;
  float scale = 1.0f / (float)(32 >> level);
  const float* fp = (level == 0) ? f0 : (level == 1) ? f1
                  : (level == 2) ? f2 : f3;
  fp += (size_t)b * 256 * H * H;

  float sx1 = x1 * scale, sy1 = y1 * scale;
  float sx2 = x2 * scale, sy2 = y2 * scale;
  float bin_w = fmaxf(sx2 - sx1, 1.0f) / 7.0f;
  float bin_h = fmaxf(sy2 - sy1, 1.0f) / 7.0f;

  int t = threadIdx.x;
  if (t < 28) {
    int   axis  = (t >= 14) ? 1 : 0;
    int   g     = t - axis * 14;
    float start = axis ? sx1 : sy1;
    float binsz = axis ? bin_w : bin_h;
    float grid  = (float)(g >> 1) + 0.25f + 0.5f * (float)(g & 1);
    int lo, hi; float fr, va;
    interp1d(start + grid * binsz, H, lo, hi, fr, va);
    s_il[axis][g] = lo; s_ih[axis][g] = hi;
    s_fr[axis][g] = fr; s_va[axis][g] = va;
  }
  __syncthreads();

  int wv = t >> 6, ln = t & 63;
  int c4 = ln * 4;
  size_t chs = (size_t)H * H;

  for (int bin = wv; bin < 49; bin += 4) {
    int oy = bin / 7, ox = bin - oy * 7;
    float a0 = 0.f, a1 = 0.f, a2 = 0.f, a3 = 0.f;
#pragma unroll
    for (int sy = 0; sy < 2; ++sy) {
#pragma unroll
      for (int sx = 0; sx < 2; ++sx) {
        int gy = oy * 2 + sy, gx = ox * 2 + sx;
        int   yl = s_il[0][gy], yh = s_ih[0][gy];
        int   xl = s_il[1][gx], xh = s_ih[1][gx];
        float fy = s_fr[0][gy], fx = s_fr[1][gx];
        float vv = s_va[0][gy] * s_va[1][gx];
        float w00 = (1.f - fy) * (1.f - fx) * vv;
        float w01 = (1.f - fy) * fx * vv;
        float w10 = fy * (1.f - fx) * vv;
        float w11 = fy * fx * vv;
        const float* base = fp + (size_t)c4 * chs;
        size_t i00 = (size_t)yl * H + xl, i01 = (size_t)yl * H + xh;
        size_t i10 = (size_t)yh * H + xl, i11 = (size_t)yh * H + xh;
#pragma unroll
        for (int k = 0; k < 4; ++k) {
          float v = w00 * base[i00 + k * chs] + w01 * base[i01 + k * chs] +
                    w10 * base[i10 + k * chs] + w11 * base[i11 + k * chs];
          if (k == 0) a0 += v; else if (k == 1) a1 += v;
          else if (k == 2) a2 += v; else a3 += v;
        }
      }
    }
    s_out[(c4 + 0) * 49 + bin] = a0 * 0.25f;
    s_out[(c4 + 1) * 49 + bin] = a1 * 0.25f;
    s_out[(c4 + 2) * 49 + bin] = a2 * 0.25f;
    s_out[(c4 + 3) * 49 + bin] = a3 * 0.25f;
  }
  __syncthreads();

  float4*       o4 = (float4*)(out + (size_t)roi * (256 * 49));
  const float4* s4 = (const float4*)s_out;
  for (int i = t; i < 256 * 49 / 4; i += 256) o4[i] = s4[i];
}

// ---------------------------------------------------------------------------
extern "C" void kernel_launch(void* const* d_in, const int* in_sizes, int n_in,
                              void* d_out, int out_size, void* d_ws, size_t ws_size,
                              hipStream_t stream) {
  const float* f[4];
  for (int i = 0; i < 4; ++i) f[i] = (const float*)d_in[i];
  const float* bb  = (const float*)d_in[4];
  float*       out = (float*)d_out;

  int B = in_sizes[0] / (256 * 32 * 32);
  int N = in_sizes[4] / 4;
  int R = N / B;

  size_t P[4] = {1024, 4096, 16384, 65536};
  size_t o1 = (size_t)B * 256 * P[0];
  size_t o2 = o1 + (size_t)B * 256 * P[1];
  size_t o3 = o2 + (size_t)B * 256 * P[2];
  size_t tot = o3 + (size_t)B * 256 * P[3];

  if (ws_size >= tot * sizeof(ushort)) {
    ushort* ws = (ushort*)d_ws;
    int n0 = B * 4 * (int)(P[0] >> 8);
    int n1 = B * 4 * (int)(P[1] >> 8);
    int n2 = B * 4 * (int)(P[2] >> 8);
    int n3 = B * 4 * (int)(P[3] >> 8);
    int c0 = n0, c1 = c0 + n1, c2 = c1 + n2, ctot = c2 + n3;
    tr_all_kernel<<<ctot, 256, 0, stream>>>(f[0], f[1], f[2], f[3], ws,
                                            c0, c1, c2, B, o1, o2, o3);
    roi_nhwc_kernel<<<N, 256, 0, stream>>>(ws, bb, out, R, o1, o2, o3);
  } else {
    roi_nchw_kernel<<<N, 256, 0, stream>>>(f[0], f[1], f[2], f[3], bb, out, R);
  }
}